// Round 2
// baseline (289.911 us; speedup 1.0000x reference)
//
#include <hip/hip_runtime.h>
#include <hip/hip_bf16.h>

// Problem: B=8, OBJ(N)=128, INP=64, HID=256, D=192.
// out[b,i,:] = relu(mean_j MLP3(relu(ea[b,i]+eb[b,j]+b_enc)) @ wd1 + bd1) @ wd2 + bd2
// Dominant cost: 131072 rows x 3 GEMMs of 256x256 = 51.5 GFLOP -> bf16 MFMA.

#define HID 256
#define NOBJ 128
#define NROW 1024   // B*NOBJ

typedef __attribute__((ext_vector_type(8))) short short8;
typedef __attribute__((ext_vector_type(4))) float float4v;

__device__ __forceinline__ unsigned short f2bf(float f) {
    unsigned int u = __builtin_bit_cast(unsigned int, f);
    u += 0x7fffu + ((u >> 16) & 1u);   // RNE
    return (unsigned short)(u >> 16);
}

// ---- prep: w1,w2,w3 (fp32 [K=256][N=256], x@w contracts K) -> bf16 transposed wt[l][n][k]
__global__ void prep_kernel(const float* __restrict__ w1, const float* __restrict__ w2,
                            const float* __restrict__ w3, unsigned short* __restrict__ wt) {
    int idx = blockIdx.x * 256 + threadIdx.x;     // 0 .. 3*65536
    int m = idx >> 16;
    int rem = idx & 65535;
    int n = rem >> 8;
    int k = rem & 255;
    const float* w = (m == 0) ? w1 : (m == 1) ? w2 : w3;
    wt[idx] = f2bf(w[k * 256 + n]);
}

// ---- encoder: ea[row][h] = x[row]@w_enc[:192] + b_enc ; eb[row][h] = x[row]@w_enc[192:]
__global__ void enc_kernel(const float* __restrict__ x0, const float* __restrict__ x1,
                           const float* __restrict__ x2, const float* __restrict__ w_enc,
                           const float* __restrict__ b_enc,
                           float* __restrict__ ea, float* __restrict__ eb) {
    __shared__ float xs[8][192];
    const int g = blockIdx.x;       // rows g*8 .. g*8+7
    const int t = threadIdx.x;      // 0..255 == output h
    for (int idx = t; idx < 8 * 192; idx += 256) {
        int r = idx / 192, d = idx % 192;
        int row = g * 8 + r;
        float v;
        if (d < 64)       v = x0[row * 64 + d];
        else if (d < 128) v = x1[row * 64 + d - 64];
        else              v = x2[row * 64 + d - 128];
        xs[r][d] = v;
    }
    __syncthreads();
    float accA[8], accB[8];
#pragma unroll
    for (int r = 0; r < 8; ++r) { accA[r] = 0.f; accB[r] = 0.f; }
    for (int d = 0; d < 192; ++d) {
        float wa = w_enc[d * 256 + t];
        float wb = w_enc[(192 + d) * 256 + t];
#pragma unroll
        for (int r = 0; r < 8; ++r) {
            accA[r] += xs[r][d] * wa;
            accB[r] += xs[r][d] * wb;
        }
    }
    float be = b_enc[t];
#pragma unroll
    for (int r = 0; r < 8; ++r) {
        int row = g * 8 + r;
        ea[row * 256 + t] = accA[r] + be;   // fold b_enc into ea
        eb[row * 256 + t] = accB[r];
    }
}

// ---- pair MLP: one workgroup per (b,i). 128 rows (j) x 3 layers of 256x256 bf16 MFMA,
//      then mean over j -> pooled[b,i][256].
__global__ __launch_bounds__(256, 2) void pair_kernel(
        const float* __restrict__ ea, const float* __restrict__ eb,
        const unsigned short* __restrict__ wt,
        const float* __restrict__ b1, const float* __restrict__ b2,
        const float* __restrict__ b3, float* __restrict__ pooled) {
    // h buffer: 128 rows x 256 bf16, XOR-swizzled in 8-element (16B) chunks:
    // elem(row,k) at row*256 + ((k>>3) ^ (row&7))*8 + (k&7)
    __shared__ __align__(16) unsigned short hbuf[32768];   // 64 KB

    const int w    = blockIdx.x;        // (b,i): b = w>>7
    const int b    = w >> 7;
    const int t    = threadIdx.x;
    const int wv   = t >> 6;            // wave 0..3
    const int lane = t & 63;
    const int lo   = lane & 15;
    const int hi   = lane >> 4;

    // preamble: h0[j][t] = relu(ea[w][t] + eb[b*128+j][t])
    // offset for (row=j, k=t): j*256 + ((t>>3)^(j&7))*8 + (t&7)
    //   = j*256 + (t ^ ((j&7)<<3))   [XOR only touches bits 3..5; t keeps bits 6..7]
    {
        float eav = ea[w * 256 + t];
        const float* ebp = eb + (b * NOBJ) * 256 + t;
        for (int j = 0; j < NOBJ; ++j) {
            float v = eav + ebp[j * 256];
            v = v > 0.f ? v : 0.f;
            int off = j * 256 + (t ^ ((j & 7) << 3));
            hbuf[off] = f2bf(v);
        }
    }
    __syncthreads();

    const int nb = wv * 64;   // this wave's 64 output columns

    for (int l = 0; l < 3; ++l) {
        const unsigned short* W = wt + l * 65536;   // [n][k] bf16
        const float* bias = (l == 0) ? b1 : (l == 1) ? b2 : b3;

        float4v acc[8][4];
#pragma unroll
        for (int nt = 0; nt < 4; ++nt) {
            float bv = bias[nb + nt * 16 + lo];
#pragma unroll
            for (int mt = 0; mt < 8; ++mt)
                acc[mt][nt] = (float4v){bv, bv, bv, bv};
        }

        for (int kb = 0; kb < 8; ++kb) {
            const int c = kb * 4 + hi;            // 16B chunk index of this lane's k
            short8 af[8];
#pragma unroll
            for (int mt = 0; mt < 8; ++mt) {
                int row = mt * 16 + lo;
                int off = row * 256 + ((c ^ (row & 7)) << 3);
                af[mt] = *(const short8*)(hbuf + off);
            }
            const int kbase = kb * 32 + hi * 8;
            short8 bf[4];
#pragma unroll
            for (int nt = 0; nt < 4; ++nt) {
                int col = nb + nt * 16 + lo;
                bf[nt] = *(const short8*)(W + col * 256 + kbase);
            }
#pragma unroll
            for (int nt = 0; nt < 4; ++nt)
#pragma unroll
                for (int mt = 0; mt < 8; ++mt)
                    acc[mt][nt] = __builtin_amdgcn_mfma_f32_16x16x32_bf16(
                        af[mt], bf[nt], acc[mt][nt], 0, 0, 0);
        }
        __syncthreads();   // all reads of hbuf done

        if (l < 2) {
            // relu -> bf16 -> hbuf (C layout: col = lo, row = hi*4 + r)
#pragma unroll
            for (int mt = 0; mt < 8; ++mt)
#pragma unroll
                for (int nt = 0; nt < 4; ++nt)
#pragma unroll
                    for (int r = 0; r < 4; ++r) {
                        int row = mt * 16 + hi * 4 + r;
                        int col = nb + nt * 16 + lo;
                        float vv = acc[mt][nt][r];
                        vv = vv > 0.f ? vv : 0.f;
                        int off = row * 256 + (((col >> 3) ^ (row & 7)) << 3) + (col & 7);
                        hbuf[off] = f2bf(vv);
                    }
            __syncthreads();
        } else {
            // layer 3: column mean over j (bias b3 already in every row's acc)
#pragma unroll
            for (int nt = 0; nt < 4; ++nt) {
                float s = 0.f;
#pragma unroll
                for (int mt = 0; mt < 8; ++mt)
#pragma unroll
                    for (int r = 0; r < 4; ++r) s += acc[mt][nt][r];
                s += __shfl_xor(s, 16);
                s += __shfl_xor(s, 32);
                if (hi == 0)
                    pooled[w * 256 + nb + nt * 16 + lo] = s * (1.f / 128.f);
            }
        }
    }
}

// ---- decoder: out[row] = relu(pooled[row]@wd1 + bd1) @ wd2 + bd2   (fp32 vector)
__global__ void dec_kernel(const float* __restrict__ pooled,
                           const float* __restrict__ wd1, const float* __restrict__ bd1,
                           const float* __restrict__ wd2, const float* __restrict__ bd2,
                           float* __restrict__ out) {
    __shared__ float ps[8][256];
    __shared__ float t1[8][257];
    const int g = blockIdx.x;       // rows g*8 .. g*8+7
    const int t = threadIdx.x;      // 0..255
#pragma unroll
    for (int r = 0; r < 8; ++r) ps[r][t] = pooled[(g * 8 + r) * 256 + t];
    __syncthreads();
    {
        float acc[8];
        float bv = bd1[t];
#pragma unroll
        for (int r = 0; r < 8; ++r) acc[r] = bv;
        for (int k = 0; k < 256; ++k) {
            float wv = wd1[k * 256 + t];
#pragma unroll
            for (int r = 0; r < 8; ++r) acc[r] += ps[r][k] * wv;
        }
#pragma unroll
        for (int r = 0; r < 8; ++r) t1[r][t] = acc[r] > 0.f ? acc[r] : 0.f;
    }
    __syncthreads();
    {
        const int o = t & 63;
        const int half = t >> 6;            // 0..3 -> rows half, half+4
        float a0 = 0.f, a1 = 0.f;
        for (int k = 0; k < 256; ++k) {
            float wv = wd2[k * 64 + o];
            a0 += t1[half][k] * wv;
            a1 += t1[half + 4][k] * wv;
        }
        float bv = bd2[o];
        out[(g * 8 + half) * 64 + o]     = a0 + bv;
        out[(g * 8 + half + 4) * 64 + o] = a1 + bv;
    }
}

extern "C" void kernel_launch(void* const* d_in, const int* in_sizes, int n_in,
                              void* d_out, int out_size, void* d_ws, size_t ws_size,
                              hipStream_t stream) {
    const float* x0    = (const float*)d_in[0];
    const float* x1    = (const float*)d_in[1];
    const float* x2    = (const float*)d_in[2];
    const float* w_enc = (const float*)d_in[3];
    const float* b_enc = (const float*)d_in[4];
    const float* w1    = (const float*)d_in[5];
    const float* b1    = (const float*)d_in[6];
    const float* w2    = (const float*)d_in[7];
    const float* b2    = (const float*)d_in[8];
    const float* w3    = (const float*)d_in[9];
    const float* b3    = (const float*)d_in[10];
    const float* wd1   = (const float*)d_in[11];
    const float* bd1   = (const float*)d_in[12];
    const float* wd2   = (const float*)d_in[13];
    const float* bd2   = (const float*)d_in[14];
    float* out = (float*)d_out;

    // workspace layout
    unsigned short* wt = (unsigned short*)d_ws;                       // 3*65536 bf16 = 384 KB
    float* ea     = (float*)((char*)d_ws + 3 * 65536 * sizeof(unsigned short));
    float* eb     = ea + NROW * HID;                                  // 1 MB each
    float* pooled = eb + NROW * HID;

    prep_kernel<<<768, 256, 0, stream>>>(w1, w2, w3, wt);
    enc_kernel<<<NROW / 8, 256, 0, stream>>>(x0, x1, x2, w_enc, b_enc, ea, eb);
    pair_kernel<<<NROW, 256, 0, stream>>>(ea, eb, wt, b1, b2, b3, pooled);
    dec_kernel<<<NROW / 8, 256, 0, stream>>>(pooled, wd1, bd1, wd2, bd2, out);
}

// Round 3
// 250.377 us; speedup vs baseline: 1.1579x; 1.1579x over previous
//
#include <hip/hip_runtime.h>
#include <hip/hip_bf16.h>
#include <stdint.h>

// B=8, OBJ=128, INP=64, HID=256, D=192.
// pair phase computes out^T = W^T · h^T per (b,i):
//   A-frags = wt[n][k] from global (k-contiguous), B-frags = h[j][k] from LDS
//   (k-contiguous), C = out^T[n][j] -> 4 consecutive n per lane = packed b64
//   writeback into next layer's [j][k] layout.

#define HID 256
#define NOBJ 128
#define NROW 1024   // B*OBJ

typedef __attribute__((ext_vector_type(8))) short short8;
typedef __attribute__((ext_vector_type(4))) float float4v;
typedef __attribute__((ext_vector_type(2))) unsigned int uint2v;

__device__ __forceinline__ unsigned int f2bf_u(float f) {
    unsigned int u = __builtin_bit_cast(unsigned int, f);
    u += 0x7fffu + ((u >> 16) & 1u);   // RNE
    return u >> 16;
}
__device__ __forceinline__ unsigned int pack2(float a, float b) {
    return f2bf_u(a) | (f2bf_u(b) << 16);
}
__device__ __forceinline__ float relu(float v) { return v > 0.f ? v : 0.f; }

// ---- setup: blocks [0,768) transpose w1..w3 -> bf16 wt[l][n][k];
//             blocks [768,1024) encoder (4 rows each, fold b_enc into ea)
__global__ void setup_kernel(const float* __restrict__ x0, const float* __restrict__ x1,
                             const float* __restrict__ x2, const float* __restrict__ w_enc,
                             const float* __restrict__ b_enc,
                             const float* __restrict__ w1, const float* __restrict__ w2,
                             const float* __restrict__ w3,
                             unsigned short* __restrict__ wt,
                             float* __restrict__ ea, float* __restrict__ eb) {
    const int bx = blockIdx.x, t = threadIdx.x;
    __shared__ float xs[4][192];
    if (bx < 768) {
        int idx = bx * 256 + t;             // 3*65536 total
        int m = idx >> 16, rem = idx & 65535, n = rem >> 8, k = rem & 255;
        const float* w = (m == 0) ? w1 : (m == 1) ? w2 : w3;
        wt[idx] = (unsigned short)f2bf_u(w[k * 256 + n]);
        return;
    }
    const int e = bx - 768;                 // 256 groups x 4 rows
    for (int idx = t; idx < 768; idx += 256) {
        int r = idx / 192, d = idx % 192;
        int row = e * 4 + r;
        float v = (d < 64) ? x0[row * 64 + d]
                : (d < 128) ? x1[row * 64 + d - 64]
                : x2[row * 64 + d - 128];
        xs[r][d] = v;
    }
    __syncthreads();
    float aA[4] = {0.f, 0.f, 0.f, 0.f}, aB[4] = {0.f, 0.f, 0.f, 0.f};
#pragma unroll 4
    for (int d = 0; d < 192; ++d) {
        float wa = w_enc[d * 256 + t];
        float wb = w_enc[(192 + d) * 256 + t];
#pragma unroll
        for (int r = 0; r < 4; ++r) { aA[r] += xs[r][d] * wa; aB[r] += xs[r][d] * wb; }
    }
    float be = b_enc[t];
#pragma unroll
    for (int r = 0; r < 4; ++r) {
        ea[(e * 4 + r) * 256 + t] = aA[r] + be;
        eb[(e * 4 + r) * 256 + t] = aB[r];
    }
}

// ---- pair MLP: grid 2048, WG = (b,i) x j-half (64 rows). 32 KB LDS h-buffer,
//      swizzled: elem(j,k) at j*256 + ((k>>3 ^ (j&31))<<3) + (k&7).
__global__ __launch_bounds__(256, 3) void pair_kernel(
        const float* __restrict__ ea, const float* __restrict__ eb,
        const unsigned short* __restrict__ wt,
        const float* __restrict__ b1, const float* __restrict__ b2,
        const float* __restrict__ b3, float* __restrict__ pp) {
    __shared__ __align__(16) unsigned short hbuf[64 * 256];   // 32 KB

    const int bx = blockIdx.x;
    const int w = bx >> 1, half = bx & 1, b = w >> 7;
    const int t = threadIdx.x, wv = t >> 6, lane = t & 63;
    const int lo = lane & 15, hi = lane >> 4;
    const int n0 = wv * 64;

    // preamble: h0[j][k] = relu(ea[w][k] + eb[b*128+half*64+j][k]); wave wv owns j=wv*16..+15
    {
        const float4v va = *(const float4v*)(ea + w * 256 + lane * 4);
        const float* ebbase = eb + (b * NOBJ + half * 64) * 256;
        const int c = lane >> 1;                 // 16B chunk of k=lane*4
        const int sub = (lane & 1) * 4;
#pragma unroll 4
        for (int jj = 0; jj < 16; ++jj) {
            const int j = wv * 16 + jj;
            float4v vb = *(const float4v*)(ebbase + j * 256 + lane * 4);
            float f0 = relu(va[0] + vb[0]);
            float f1 = relu(va[1] + vb[1]);
            float f2 = relu(va[2] + vb[2]);
            float f3 = relu(va[3] + vb[3]);
            int addr = j * 256 + ((c ^ (j & 31)) << 3) + sub;
            *(uint2v*)(hbuf + addr) = (uint2v){pack2(f0, f1), pack2(f2, f3)};
        }
    }
    __syncthreads();

    int jbase[4], jx[4];
#pragma unroll
    for (int jt = 0; jt < 4; ++jt) {
        int jr = jt * 16 + lo;
        jbase[jt] = jr * 256;
        jx[jt] = jr & 31;
    }
    const unsigned short* aptr = wt + (n0 + lo) * 256 + hi * 8;

    float4v acc[4][4];   // [nt][jt]
#pragma unroll
    for (int l = 0; l < 3; ++l) {
        const unsigned short* W = aptr + l * 65536;
        const float* bias = (l == 0) ? b1 : (l == 1) ? b2 : b3;

#pragma unroll
        for (int nt = 0; nt < 4; ++nt) {
            float4v bv = *(const float4v*)(bias + n0 + nt * 16 + hi * 4);
#pragma unroll
            for (int jt = 0; jt < 4; ++jt) acc[nt][jt] = bv;
        }

        short8 af[2][4], bfr[2][4];
#pragma unroll
        for (int nt = 0; nt < 4; ++nt)
            af[0][nt] = *(const short8*)(W + nt * 4096);
#pragma unroll
        for (int jt = 0; jt < 4; ++jt)
            bfr[0][jt] = *(const short8*)(hbuf + jbase[jt] + ((hi ^ jx[jt]) << 3));
#pragma unroll
        for (int kb = 0; kb < 8; ++kb) {
            const int cur = kb & 1, nxt = cur ^ 1;
            if (kb < 7) {
#pragma unroll
                for (int nt = 0; nt < 4; ++nt)
                    af[nxt][nt] = *(const short8*)(W + nt * 4096 + (kb + 1) * 32);
#pragma unroll
                for (int jt = 0; jt < 4; ++jt)
                    bfr[nxt][jt] = *(const short8*)(hbuf + jbase[jt] +
                                       ((((kb + 1) * 4 + hi) ^ jx[jt]) << 3));
            }
#pragma unroll
            for (int nt = 0; nt < 4; ++nt)
#pragma unroll
                for (int jt = 0; jt < 4; ++jt)
                    acc[nt][jt] = __builtin_amdgcn_mfma_f32_16x16x32_bf16(
                        af[cur][nt], bfr[cur][jt], acc[nt][jt], 0, 0, 0);
        }
        __syncthreads();   // all hbuf reads of this layer done

        if (l < 2) {
            // C: rows n = n0+nt*16+hi*4+{0..3} (contiguous!), col j = jt*16+lo
#pragma unroll
            for (int nt = 0; nt < 4; ++nt) {
                const int nb_ = n0 + nt * 16 + hi * 4;
                const int cn = nb_ >> 3, sub = nb_ & 7;
#pragma unroll
                for (int jt = 0; jt < 4; ++jt) {
                    float4v v = acc[nt][jt];
                    int j = jt * 16 + lo;
                    int addr = j * 256 + ((cn ^ (j & 31)) << 3) + sub;
                    *(uint2v*)(hbuf + addr) = (uint2v){
                        pack2(relu(v[0]), relu(v[1])),
                        pack2(relu(v[2]), relu(v[3]))};
                }
            }
            __syncthreads();
        } else {
            // partial mean over this WG's 64 j (b3 included per row: /128 later + dec sums halves)
#pragma unroll
            for (int nt = 0; nt < 4; ++nt) {
#pragma unroll
                for (int r = 0; r < 4; ++r) {
                    float s = acc[nt][0][r] + acc[nt][1][r] + acc[nt][2][r] + acc[nt][3][r];
                    s += __shfl_xor(s, 1);
                    s += __shfl_xor(s, 2);
                    s += __shfl_xor(s, 4);
                    s += __shfl_xor(s, 8);
                    if (lo == 0)
                        pp[half * (NROW * HID) + w * 256 + n0 + nt * 16 + hi * 4 + r]
                            = s * 0.0078125f;
                }
            }
        }
    }
}

// ---- decoder: 256 WGs x 4 rows. ps = pp_half0 + pp_half1 (= mean + b3).
__global__ void dec_kernel(const float* __restrict__ pp,
                           const float* __restrict__ wd1, const float* __restrict__ bd1,
                           const float* __restrict__ wd2, const float* __restrict__ bd2,
                           float* __restrict__ out) {
    __shared__ float ps[4][256];
    __shared__ float t1[4][260];
    const int g = blockIdx.x, t = threadIdx.x;
#pragma unroll
    for (int r = 0; r < 4; ++r) {
        int row = g * 4 + r;
        ps[r][t] = pp[row * 256 + t] + pp[NROW * HID + row * 256 + t];
    }
    __syncthreads();
    {
        float acc[4];
        float bv = bd1[t];
#pragma unroll
        for (int r = 0; r < 4; ++r) acc[r] = bv;
#pragma unroll 4
        for (int k = 0; k < 256; ++k) {
            float wv = wd1[k * 256 + t];
#pragma unroll
            for (int r = 0; r < 4; ++r) acc[r] += ps[r][k] * wv;
        }
#pragma unroll
        for (int r = 0; r < 4; ++r) t1[r][t] = relu(acc[r]);
    }
    __syncthreads();
    {
        const int o = t & 63, rr = t >> 6;
        float a = 0.f;
#pragma unroll 4
        for (int k = 0; k < 256; ++k) a += t1[rr][k] * wd2[k * 64 + o];
        out[(g * 4 + rr) * 64 + o] = a + bd2[o];
    }
}

extern "C" void kernel_launch(void* const* d_in, const int* in_sizes, int n_in,
                              void* d_out, int out_size, void* d_ws, size_t ws_size,
                              hipStream_t stream) {
    const float* x0    = (const float*)d_in[0];
    const float* x1    = (const float*)d_in[1];
    const float* x2    = (const float*)d_in[2];
    const float* w_enc = (const float*)d_in[3];
    const float* b_enc = (const float*)d_in[4];
    const float* w1    = (const float*)d_in[5];
    const float* b1    = (const float*)d_in[6];
    const float* w2    = (const float*)d_in[7];
    const float* b2    = (const float*)d_in[8];
    const float* w3    = (const float*)d_in[9];
    const float* b3    = (const float*)d_in[10];
    const float* wd1   = (const float*)d_in[11];
    const float* bd1   = (const float*)d_in[12];
    const float* wd2   = (const float*)d_in[13];
    const float* bd2   = (const float*)d_in[14];
    float* out = (float*)d_out;

    // workspace: wt (384KB) | ea (1MB) | eb (1MB) | pp (2MB, two j-halves)
    unsigned short* wt = (unsigned short*)d_ws;
    float* ea = (float*)((char*)d_ws + 3 * 65536 * sizeof(unsigned short));
    float* eb = ea + NROW * HID;
    float* pp = eb + NROW * HID;

    setup_kernel<<<1024, 256, 0, stream>>>(x0, x1, x2, w_enc, b_enc, w1, w2, w3, wt, ea, eb);
    pair_kernel<<<2048, 256, 0, stream>>>(ea, eb, wt, b1, b2, b3, pp);
    dec_kernel<<<256, 256, 0, stream>>>(pp, wd1, bd1, wd2, bd2, out);
}